// Round 2
// baseline (1956.910 us; speedup 1.0000x reference)
//
#include <hip/hip_runtime.h>
#include <hip/hip_bf16.h>

typedef __hip_bfloat16 bf16;

__device__ __forceinline__ float ldconv(const float* p, size_t i) { return p[i]; }
__device__ __forceinline__ float ldconv(const bf16* p, size_t i) { return __bfloat162float(p[i]); }
__device__ __forceinline__ void stconv(float* p, size_t i, float v) { p[i] = v; }
__device__ __forceinline__ void stconv(bf16* p, size_t i, float v) { p[i] = __float2bfloat16(v); }

// Generic tiled fp32-accumulate GEMM: C = epi(A@B + bias)
// BM=BN=128, BK=8, 256 threads, 8x8 per-thread microtile.
// EPI: 0 = none, 1 = SiLU, 2 = row-scale (post-bias multiply by rowscale[m])
// M, N multiples of 128; K may be ragged. ldb = row stride of B.
template<typename TA, typename TC, int EPI>
__global__ __launch_bounds__(256) void gemm_tile(
    const TA* __restrict__ A, const float* __restrict__ B,
    const float* __restrict__ bias, const float* __restrict__ rowscale,
    TC* __restrict__ C, int M, int K, int N, int ldb)
{
    __shared__ float As[8][128];
    __shared__ float Bs[8][128];
    const int tid = threadIdx.x;
    const size_t m0 = (size_t)blockIdx.x * 128;
    const int n0 = blockIdx.y * 128;
    const int tx = tid & 15;
    const int ty = tid >> 4;
    const int row = ty * 8;
    const int col = tx * 8;

    float acc[8][8];
#pragma unroll
    for (int i = 0; i < 8; ++i)
#pragma unroll
        for (int j = 0; j < 8; ++j) acc[i][j] = 0.f;

    for (int k0 = 0; k0 < K; k0 += 8) {
#pragma unroll
        for (int i = 0; i < 4; ++i) {
            int e = tid + 256 * i;
            int m = e >> 3;
            int k = e & 7;
            float v = 0.f;
            if (k0 + k < K) v = ldconv(A, (m0 + m) * (size_t)K + (k0 + k));
            As[k][m] = v;
        }
        {
            int k = tid >> 5;
            int nq = (tid & 31) * 4;
            float4 v = make_float4(0.f, 0.f, 0.f, 0.f);
            if (k0 + k < K) v = *(const float4*)(B + (size_t)(k0 + k) * ldb + n0 + nq);
            Bs[k][nq]     = v.x;
            Bs[k][nq + 1] = v.y;
            Bs[k][nq + 2] = v.z;
            Bs[k][nq + 3] = v.w;
        }
        __syncthreads();
#pragma unroll
        for (int k = 0; k < 8; ++k) {
            float a[8], b[8];
#pragma unroll
            for (int i = 0; i < 8; ++i) a[i] = As[k][row + i];
#pragma unroll
            for (int j = 0; j < 8; ++j) b[j] = Bs[k][col + j];
#pragma unroll
            for (int i = 0; i < 8; ++i)
#pragma unroll
                for (int j = 0; j < 8; ++j) acc[i][j] = fmaf(a[i], b[j], acc[i][j]);
        }
        __syncthreads();
    }

#pragma unroll
    for (int i = 0; i < 8; ++i) {
        size_t m = m0 + row + i;
        float rs = 1.f;
        if (EPI == 2) rs = rowscale[m];
#pragma unroll
        for (int j = 0; j < 8; ++j) {
            float v = acc[i][j];
            if (bias) v += bias[n0 + col + j];
            if (EPI == 1) v = v / (1.f + expf(-v));   // SiLU
            if (EPI == 2) v *= rs;
            stconv(C, m * (size_t)N + (n0 + col + j), v);
        }
    }
}

__global__ __launch_bounds__(256) void zero_k(float4* __restrict__ p, size_t n4)
{
    size_t i = (size_t)blockIdx.x * 256 + threadIdx.x;
    if (i < n4) p[i] = make_float4(0.f, 0.f, 0.f, 0.f);
}

// Per-edge message computation + atomic scatter into d_out accumulators.
// Processes edges [e0, e0+EC). filt is the bf16 filter chunk (local-indexed).
__global__ __launch_bounds__(256) void edge_agg(
    const bf16* __restrict__ x, const bf16* __restrict__ filt,
    const float* __restrict__ mu, const int* __restrict__ ei,
    const float* __restrict__ uv,
    float* __restrict__ outq, float* __restrict__ outmu,
    float* __restrict__ deg, int e0, int EC, int E)
{
    int t = blockIdx.x * 256 + threadIdx.x;
    int le = t >> 7;
    int h = t & 127;
    if (le >= EC) return;
    int e = e0 + le;
    int tgt = ei[e];
    int src = ei[E + e];

    size_t fe = (size_t)le * 384;
    size_t xs = (size_t)src * 384;
    float fq = __bfloat162float(filt[fe + h]);
    float fr = __bfloat162float(filt[fe + 128 + h]);
    float fm = __bfloat162float(filt[fe + 256 + h]);

    float xq = __bfloat162float(x[xs + h]) * fq;
    float xr = __bfloat162float(x[xs + 128 + h]) * fr;
    float xm = __bfloat162float(x[xs + 256 + h]) * fm;

    float u0 = uv[e * 3 + 0];
    float u1 = uv[e * 3 + 1];
    float u2 = uv[e * 3 + 2];
    const float* mus = mu + (size_t)src * 384;

    atomicAdd(&outq[(size_t)tgt * 128 + h], xq);
    size_t mb = (size_t)tgt * 384 + h;
    atomicAdd(&outmu[mb],       fmaf(u0, xr, mus[h] * xm));
    atomicAdd(&outmu[mb + 128], fmaf(u1, xr, mus[128 + h] * xm));
    atomicAdd(&outmu[mb + 256], fmaf(u2, xr, mus[256 + h] * xm));
    if (h == 0) atomicAdd(&deg[tgt], 1.f);
}

// In place: outq = q + outq/deg ; outmu = mu + outmu/deg
__global__ __launch_bounds__(256) void finalize_k(
    const float* __restrict__ q, const float* __restrict__ mu,
    const float* __restrict__ deg,
    float* __restrict__ outq, float* __restrict__ outmu, int N)
{
    int i = blockIdx.x * 256 + threadIdx.x;
    if (i >= N * 128) return;
    int n = i >> 7;
    int h = i & 127;
    float inv = 1.f / fmaxf(deg[n], 1.f);
    outq[i] = q[i] + outq[i] * inv;
    size_t b = (size_t)n * 384 + h;
    outmu[b]       = mu[b]       + outmu[b]       * inv;
    outmu[b + 128] = mu[b + 128] + outmu[b + 128] * inv;
    outmu[b + 256] = mu[b + 256] + outmu[b + 256] * inv;
}

// From mu_cat chunk (f32, local rows (nl*3+c)): scin=[q|norm], inner=<v,w>
__global__ __launch_bounds__(256) void mix_pre(
    const float* __restrict__ mcat, const float* __restrict__ outq,
    bf16* __restrict__ scin, bf16* __restrict__ inner, int n0, int NC)
{
    int i = blockIdx.x * 256 + threadIdx.x;
    if (i >= NC * 128) return;
    int nl = i >> 7;
    int h = i & 127;
    size_t n = (size_t)(n0 + nl);
    size_t r = (size_t)nl * 768;
    float v0 = mcat[r + h],       w0 = mcat[r + 128 + h];
    float v1 = mcat[r + 256 + h], w1 = mcat[r + 384 + h];
    float v2 = mcat[r + 512 + h], w2 = mcat[r + 640 + h];
    float nrm = sqrtf(v0 * v0 + v1 * v1 + v2 * v2 + 1e-8f);
    inner[n * 128 + h] = __float2bfloat16(v0 * w0 + v1 * w1 + v2 * w2);
    scin[n * 256 + h] = __float2bfloat16(outq[n * 128 + h]);
    scin[n * 256 + 128 + h] = __float2bfloat16(nrm);
}

// q += dq + dqmu*inner ; mu += mu_w * dmu_scale   (w chunk recomputed, local rows)
__global__ __launch_bounds__(256) void mix_post(
    const bf16* __restrict__ delta, const bf16* __restrict__ inner,
    const float* __restrict__ w,
    float* __restrict__ outq, float* __restrict__ outmu, int n0, int NC)
{
    int i = blockIdx.x * 256 + threadIdx.x;
    if (i >= NC * 128) return;
    int nl = i >> 7;
    int h = i & 127;
    size_t n = (size_t)(n0 + nl);
    size_t dr = n * 384;
    float dq  = __bfloat162float(delta[dr + h]);
    float dsc = __bfloat162float(delta[dr + 128 + h]);
    float dqm = __bfloat162float(delta[dr + 256 + h]);
    outq[n * 128 + h] += dq + dqm * __bfloat162float(inner[n * 128 + h]);
    size_t wb = (size_t)nl * 384 + h;
    size_t mb = n * 384 + h;
    outmu[mb]       += w[wb]       * dsc;
    outmu[mb + 128] += w[wb + 128] * dsc;
    outmu[mb + 256] += w[wb + 256] * dsc;
}

extern "C" void kernel_launch(void* const* d_in, const int* in_sizes, int n_in,
                              void* d_out, int out_size, void* d_ws, size_t ws_size,
                              hipStream_t stream)
{
    const float* q   = (const float*)d_in[0];
    const float* mu  = (const float*)d_in[1];
    const int*   ei  = (const int*)d_in[2];
    const float* rbf = (const float*)d_in[3];
    const float* uv  = (const float*)d_in[4];
    const float* cut = (const float*)d_in[5];
    const float* Wi1 = (const float*)d_in[6];
    const float* bi1 = (const float*)d_in[7];
    const float* Wi2 = (const float*)d_in[8];
    const float* bi2 = (const float*)d_in[9];
    const float* Wf1 = (const float*)d_in[10];
    const float* bf1 = (const float*)d_in[11];
    const float* Wf2 = (const float*)d_in[12];
    const float* bf2 = (const float*)d_in[13];
    const float* Wv  = (const float*)d_in[14];
    const float* Ws1 = (const float*)d_in[15];
    const float* bs1 = (const float*)d_in[16];
    const float* Ws2 = (const float*)d_in[17];
    const float* bs2 = (const float*)d_in[18];

    const int H = 128;
    const int N = in_sizes[0] / H;       // 32768
    const int E = in_sizes[5];           // 262144
    (void)n_in; (void)out_size;

    // ---- workspace pool: 58.85 MB total, phase-aliased ----
    // slotA (25,165,824 B): x1b -> filters_chunk -> scin -> delta
    // slotB (25,165,824 B): xbf -> mu_cat_chunk -> s1 -> w_chunk
    // slotC ( 8,388,608 B): hf_chunk -> inner
    // deg   (   131,072 B)
    char* ws = (char*)d_ws;
    const size_t SZA = (size_t)N * 384 * 2;
    const size_t SZB = (size_t)N * 384 * 2;
    const size_t SZC = (size_t)N * 128 * 2;
    bf16* slotA = (bf16*)ws;
    bf16* slotB = (bf16*)(ws + SZA);
    bf16* slotC = (bf16*)(ws + SZA + SZB);
    float* deg  = (float*)(ws + SZA + SZB + SZC);
    if (ws_size < SZA + SZB + SZC + (size_t)N * 4) return;

    float* outq  = (float*)d_out;
    float* outmu = outq + (size_t)N * 128;

    dim3 blk(256);

    // ---- interaction MLP: x = silu(q@Wi1+bi1)@Wi2+bi2 -> bf16 ----
    bf16* x1b = slotA;
    bf16* xbf = slotB;
    gemm_tile<float, bf16, 1><<<dim3(N / 128, 3), blk, 0, stream>>>(
        q, Wi1, bi1, nullptr, x1b, N, 128, 384, 384);
    gemm_tile<bf16, bf16, 0><<<dim3(N / 128, 3), blk, 0, stream>>>(
        x1b, Wi2, bi2, nullptr, xbf, N, 384, 384, 384);

    // ---- zero the message accumulators (d_out itself) + deg ----
    zero_k<<<dim3((unsigned)((size_t)N * 512 / 4 / 256)), blk, 0, stream>>>(
        (float4*)d_out, (size_t)N * 512 / 4);
    zero_k<<<dim3((unsigned)(N / 4 / 256) + 1), blk, 0, stream>>>(
        (float4*)deg, (size_t)N / 4);

    // ---- filter network + edge aggregation, chunked over edges ----
    {
        const int EC = 32768;               // 8 chunks
        bf16* filc = slotA;                 // x1b dead
        bf16* hfc  = slotC;
        for (int e0 = 0; e0 < E; e0 += EC) {
            gemm_tile<float, bf16, 1><<<dim3(EC / 128, 1), blk, 0, stream>>>(
                rbf + (size_t)e0 * 20, Wf1, bf1, nullptr, hfc, EC, 20, 128, 128);
            gemm_tile<bf16, bf16, 2><<<dim3(EC / 128, 3), blk, 0, stream>>>(
                hfc, Wf2, bf2, cut + e0, filc, EC, 128, 384, 384);
            edge_agg<<<dim3(EC / 2), blk, 0, stream>>>(
                xbf, filc, mu, ei, uv, outq, outmu, deg, e0, EC, E);
        }
    }

    // ---- q_new / mu_new in place on d_out ----
    finalize_k<<<dim3(N * 128 / 256), blk, 0, stream>>>(q, mu, deg, outq, outmu, N);

    // ---- mixing: mu_cat chunks -> scin/inner ----
    bf16* scin  = slotA;
    bf16* inner = slotC;
    {
        const int NC = 8192;                // 4 chunks
        float* mcat = (float*)slotB;        // xbf dead
        for (int n0 = 0; n0 < N; n0 += NC) {
            gemm_tile<float, float, 0><<<dim3(3 * NC / 128, 2), blk, 0, stream>>>(
                outmu + (size_t)n0 * 384, Wv, nullptr, nullptr, mcat,
                3 * NC, 128, 256, 256);
            mix_pre<<<dim3(NC * 128 / 256), blk, 0, stream>>>(
                mcat, outq, scin, inner, n0, NC);
        }
    }

    // ---- scalar MLP: delta = silu(scin@Ws1+bs1)@Ws2+bs2 ----
    bf16* s1 = slotB;
    gemm_tile<bf16, bf16, 1><<<dim3(N / 128, 3), blk, 0, stream>>>(
        scin, Ws1, bs1, nullptr, s1, N, 256, 384, 384);
    bf16* delta = slotA;                    // scin dead
    gemm_tile<bf16, bf16, 0><<<dim3(N / 128, 3), blk, 0, stream>>>(
        s1, Ws2, bs2, nullptr, delta, N, 384, 384, 384);

    // ---- final update: recompute mu_w in chunks, apply ----
    {
        const int NC = 8192;
        float* wchunk = (float*)slotB;      // s1 dead
        for (int n0 = 0; n0 < N; n0 += NC) {
            gemm_tile<float, float, 0><<<dim3(3 * NC / 128, 1), blk, 0, stream>>>(
                outmu + (size_t)n0 * 384, Wv + 128, nullptr, nullptr, wchunk,
                3 * NC, 128, 128, 256);
            mix_post<<<dim3(NC * 128 / 256), blk, 0, stream>>>(
                delta, inner, wchunk, outq, outmu, n0, NC);
        }
    }
}

// Round 3
// 1383.462 us; speedup vs baseline: 1.4145x; 1.4145x over previous
//
#include <hip/hip_runtime.h>
#include <hip/hip_bf16.h>

typedef __hip_bfloat16 bf16;
typedef __attribute__((ext_vector_type(8))) short bf16x8;
typedef __attribute__((ext_vector_type(4))) short bf16x4v;
typedef __attribute__((ext_vector_type(4))) float f32x4;

// ---------------------------------------------------------------------------
// MFMA bf16 GEMM: C = epi(A @ Bt^T + bias)
//   A:  [M][K]  TA=bf16: row stride K (K%32==0).
//               TA=float: row stride ka; logical K%32==0, cols k>=ka are 0.
//   Bt: [N][K]  bf16 (weights pre-transposed), row stride K.
//   C:  [M][N]  (bf16 or float)
//   M%128==0, N%128==0.
// Block: 256 threads = 4 waves (2x2), each wave 64x64 via 4x4 MFMA 16x16x32.
// EPI: 0 none, 1 SiLU, 2 rowscale (post-bias multiply by rowscale[m])
// ---------------------------------------------------------------------------
template<typename TA, typename TC, int EPI>
__global__ __launch_bounds__(256) void mgemm(
    const TA* __restrict__ A, const bf16* __restrict__ Bt,
    const float* __restrict__ bias, const float* __restrict__ rowscale,
    TC* __restrict__ C, int M, int K, int N, int ka)
{
    __shared__ __align__(16) bf16 As[128 * 32];
    __shared__ __align__(16) bf16 Bs[128 * 32];
    const int tid = threadIdx.x;
    const int lane = tid & 63;
    const int wave = tid >> 6;
    const int col16 = lane & 15;
    const int quad = lane >> 4;
    const int wm = (wave & 1) * 64;
    const int wn = (wave >> 1) * 64;
    const size_t m0 = (size_t)blockIdx.x * 128;
    const int n0 = blockIdx.y * 128;

    f32x4 acc[4][4];
#pragma unroll
    for (int i = 0; i < 4; ++i)
#pragma unroll
        for (int j = 0; j < 4; ++j) acc[i][j] = (f32x4){0.f, 0.f, 0.f, 0.f};

    for (int k0 = 0; k0 < K; k0 += 32) {
        // ---- stage A tile [128 rows][32 k] ----
        if constexpr (sizeof(TA) == 2) {
#pragma unroll
            for (int r = 0; r < 2; ++r) {
                int p = tid + 256 * r;
                int row = p >> 2, kp = p & 3;
                *(bf16x8*)(As + row * 32 + kp * 8) =
                    *(const bf16x8*)((const bf16*)A + (m0 + row) * (size_t)K + k0 + kp * 8);
            }
        } else {
#pragma unroll
            for (int r = 0; r < 4; ++r) {
                int p = tid + 256 * r;
                int row = p >> 3, kp = p & 7;
                int kg = k0 + kp * 4;
                float4 v = make_float4(0.f, 0.f, 0.f, 0.f);
                if (kg < ka) v = *(const float4*)((const float*)A + (m0 + row) * (size_t)ka + kg);
                bf16 t[4] = {__float2bfloat16(v.x), __float2bfloat16(v.y),
                             __float2bfloat16(v.z), __float2bfloat16(v.w)};
                *(bf16x4v*)(As + row * 32 + kp * 4) = *(const bf16x4v*)t;
            }
        }
        // ---- stage B tile [128 n][32 k] from Bt ----
#pragma unroll
        for (int r = 0; r < 2; ++r) {
            int p = tid + 256 * r;
            int row = p >> 2, kp = p & 3;
            *(bf16x8*)(Bs + row * 32 + kp * 8) =
                *(const bf16x8*)(Bt + (n0 + row) * (size_t)K + k0 + kp * 8);
        }
        __syncthreads();

        bf16x8 a[4], b[4];
#pragma unroll
        for (int i = 0; i < 4; ++i)
            a[i] = *(const bf16x8*)(As + (wm + i * 16 + col16) * 32 + quad * 8);
#pragma unroll
        for (int j = 0; j < 4; ++j)
            b[j] = *(const bf16x8*)(Bs + (wn + j * 16 + col16) * 32 + quad * 8);
#pragma unroll
        for (int i = 0; i < 4; ++i)
#pragma unroll
            for (int j = 0; j < 4; ++j)
                acc[i][j] = __builtin_amdgcn_mfma_f32_16x16x32_bf16(a[i], b[j], acc[i][j], 0, 0, 0);
        __syncthreads();
    }

    // ---- epilogue: C[row = m0+wm+i*16+quad*4+r][col = n0+wn+j*16+col16] ----
#pragma unroll
    for (int j = 0; j < 4; ++j) {
        int col = n0 + wn + j * 16 + col16;
        float bv = bias ? bias[col] : 0.f;
#pragma unroll
        for (int i = 0; i < 4; ++i) {
#pragma unroll
            for (int r = 0; r < 4; ++r) {
                size_t row = m0 + wm + i * 16 + quad * 4 + r;
                float v = acc[i][j][r] + bv;
                if (EPI == 1) v = v / (1.f + expf(-v));
                if (EPI == 2) v *= rowscale[row];
                if constexpr (sizeof(TC) == 2)
                    ((bf16*)C)[row * (size_t)N + col] = __float2bfloat16(v);
                else
                    ((float*)C)[row * (size_t)N + col] = v;
            }
        }
    }
}

// Weight transpose+convert: in fp32 [K][Nc] -> out bf16 [Nc][Kp], zero-pad k>=K.
__global__ __launch_bounds__(256) void cvt_w(
    const float* __restrict__ in, bf16* __restrict__ out, int K, int Nc, int Kp)
{
    int i = blockIdx.x * 256 + threadIdx.x;
    if (i >= Nc * Kp) return;
    int n = i / Kp, k = i % Kp;
    out[i] = __float2bfloat16(k < K ? in[(size_t)k * Nc + n] : 0.f);
}

__global__ __launch_bounds__(256) void zero_k(float4* __restrict__ p, size_t n4)
{
    size_t i = (size_t)blockIdx.x * 256 + threadIdx.x;
    if (i < n4) p[i] = make_float4(0.f, 0.f, 0.f, 0.f);
}

// Per-edge messages + atomic scatter into d_out accumulators. 2 edges/block.
__global__ __launch_bounds__(256) void edge_agg(
    const bf16* __restrict__ x, const bf16* __restrict__ filt,
    const float* __restrict__ mu, const int* __restrict__ ei,
    const float* __restrict__ uv,
    float* __restrict__ outq, float* __restrict__ outmu,
    float* __restrict__ deg, int e0, int EC, int E)
{
    int t = blockIdx.x * 256 + threadIdx.x;
    int le = t >> 7;
    int h = t & 127;
    if (le >= EC) return;
    int e = e0 + le;
    int tgt = ei[e];
    int src = ei[E + e];

    size_t fe = (size_t)le * 384;
    size_t xs = (size_t)src * 384;
    float fq = __bfloat162float(filt[fe + h]);
    float fr = __bfloat162float(filt[fe + 128 + h]);
    float fm = __bfloat162float(filt[fe + 256 + h]);

    float xq = __bfloat162float(x[xs + h]) * fq;
    float xr = __bfloat162float(x[xs + 128 + h]) * fr;
    float xm = __bfloat162float(x[xs + 256 + h]) * fm;

    float u0 = uv[e * 3 + 0];
    float u1 = uv[e * 3 + 1];
    float u2 = uv[e * 3 + 2];
    const float* mus = mu + (size_t)src * 384;

    atomicAdd(&outq[(size_t)tgt * 128 + h], xq);
    size_t mb = (size_t)tgt * 384 + h;
    atomicAdd(&outmu[mb],       fmaf(u0, xr, mus[h] * xm));
    atomicAdd(&outmu[mb + 128], fmaf(u1, xr, mus[128 + h] * xm));
    atomicAdd(&outmu[mb + 256], fmaf(u2, xr, mus[256 + h] * xm));
    if (h == 0) atomicAdd(&deg[tgt], 1.f);
}

// In place: outq = q + outq/deg ; outmu = mu + outmu/deg
__global__ __launch_bounds__(256) void finalize_k(
    const float* __restrict__ q, const float* __restrict__ mu,
    const float* __restrict__ deg,
    float* __restrict__ outq, float* __restrict__ outmu, int N)
{
    int i = blockIdx.x * 256 + threadIdx.x;
    if (i >= N * 128) return;
    int n = i >> 7;
    int h = i & 127;
    float inv = 1.f / fmaxf(deg[n], 1.f);
    outq[i] = q[i] + outq[i] * inv;
    size_t b = (size_t)n * 384 + h;
    outmu[b]       = mu[b]       + outmu[b]       * inv;
    outmu[b + 128] = mu[b + 128] + outmu[b + 128] * inv;
    outmu[b + 256] = mu[b + 256] + outmu[b + 256] * inv;
}

// From mcat chunk (f32 rows (nl*3+c), 256 cols): scin=[q|norm] bf16, inner f32
__global__ __launch_bounds__(256) void mix_pre(
    const float* __restrict__ mcat, const float* __restrict__ outq,
    bf16* __restrict__ scin, float* __restrict__ inner, int NC)
{
    int i = blockIdx.x * 256 + threadIdx.x;
    if (i >= NC * 128) return;
    int nl = i >> 7;
    int h = i & 127;
    size_t r = (size_t)nl * 768;
    float v0 = mcat[r + h],       w0 = mcat[r + 128 + h];
    float v1 = mcat[r + 256 + h], w1 = mcat[r + 384 + h];
    float v2 = mcat[r + 512 + h], w2 = mcat[r + 640 + h];
    float nrm = sqrtf(v0 * v0 + v1 * v1 + v2 * v2 + 1e-8f);
    inner[i] = v0 * w0 + v1 * w1 + v2 * w2;
    scin[(size_t)nl * 256 + h] = __float2bfloat16(outq[i]);
    scin[(size_t)nl * 256 + 128 + h] = __float2bfloat16(nrm);
}

// q += dq + dqmu*inner ; mu += mu_w * dmu_scale  (mu_w read from mcat cols 128:256)
__global__ __launch_bounds__(256) void mix_post(
    const bf16* __restrict__ delta, const float* __restrict__ inner,
    const float* __restrict__ mcat,
    float* __restrict__ outq, float* __restrict__ outmu, int n0, int NC)
{
    int i = blockIdx.x * 256 + threadIdx.x;
    if (i >= NC * 128) return;
    int nl = i >> 7;
    int h = i & 127;
    size_t n = (size_t)(n0 + nl);
    size_t dr = (size_t)nl * 384;
    float dq  = __bfloat162float(delta[dr + h]);
    float dsc = __bfloat162float(delta[dr + 128 + h]);
    float dqm = __bfloat162float(delta[dr + 256 + h]);
    outq[n * 128 + h] += dq + dqm * inner[i];
    size_t r = (size_t)nl * 768;
    size_t mb = n * 384 + h;
    outmu[mb]       += mcat[r + 128 + h] * dsc;
    outmu[mb + 128] += mcat[r + 384 + h] * dsc;
    outmu[mb + 256] += mcat[r + 640 + h] * dsc;
}

extern "C" void kernel_launch(void* const* d_in, const int* in_sizes, int n_in,
                              void* d_out, int out_size, void* d_ws, size_t ws_size,
                              hipStream_t stream)
{
    const float* q   = (const float*)d_in[0];
    const float* mu  = (const float*)d_in[1];
    const int*   ei  = (const int*)d_in[2];
    const float* rbf = (const float*)d_in[3];
    const float* uv  = (const float*)d_in[4];
    const float* cut = (const float*)d_in[5];
    const float* Wi1 = (const float*)d_in[6];
    const float* bi1 = (const float*)d_in[7];
    const float* Wi2 = (const float*)d_in[8];
    const float* bi2 = (const float*)d_in[9];
    const float* Wf1 = (const float*)d_in[10];
    const float* bf1 = (const float*)d_in[11];
    const float* Wf2 = (const float*)d_in[12];
    const float* bf2 = (const float*)d_in[13];
    const float* Wv  = (const float*)d_in[14];
    const float* Ws1 = (const float*)d_in[15];
    const float* bs1 = (const float*)d_in[16];
    const float* Ws2 = (const float*)d_in[17];
    const float* bs2 = (const float*)d_in[18];

    const int H = 128;
    const int N = in_sizes[0] / H;   // 32768
    const int E = in_sizes[5];       // 262144
    (void)n_in; (void)out_size;

    // ---- workspace pool (~51.5 MB, phase-aliased) ----
    char* ws = (char*)d_ws;
    const size_t SZ_A = (size_t)16384 * 384 * 2;        // 12.58 MB: filc / mcat
    const size_t SZ_B = (size_t)N * 384 * 2;            // 25.17 MB: xb / mix bufs
    const size_t SZ_P = (size_t)16384 * 384 * 2;        // 12.58 MB: x1b_c / hf
    bf16*  slotA = (bf16*)ws;
    bf16*  xb    = (bf16*)(ws + SZ_A);
    bf16*  slotP = (bf16*)(ws + SZ_A + SZ_B);
    float* deg   = (float*)(ws + SZ_A + SZ_B + SZ_P);
    bf16*  wts   = (bf16*)(ws + SZ_A + SZ_B + SZ_P + (size_t)N * 4);
    if (ws_size < SZ_A + SZ_B + SZ_P + (size_t)N * 4 + 1100000) return;

    bf16* Wi1t = wts;             // [384][128]
    bf16* Wi2t = Wi1t + 49152;    // [384][384]
    bf16* Wf1t = Wi2t + 147456;   // [128][32]
    bf16* Wf2t = Wf1t + 4096;     // [384][128]
    bf16* Wvt  = Wf2t + 49152;    // [256][128]
    bf16* Ws1t = Wvt  + 32768;    // [384][256]
    bf16* Ws2t = Ws1t + 98304;    // [384][384]

    float* outq  = (float*)d_out;
    float* outmu = outq + (size_t)N * 128;

    dim3 blk(256);

    // ---- P0: weights -> bf16 transposed ----
    cvt_w<<<dim3(192), blk, 0, stream>>>(Wi1, Wi1t, 128, 384, 128);
    cvt_w<<<dim3(576), blk, 0, stream>>>(Wi2, Wi2t, 384, 384, 384);
    cvt_w<<<dim3(16),  blk, 0, stream>>>(Wf1, Wf1t, 20, 128, 32);
    cvt_w<<<dim3(192), blk, 0, stream>>>(Wf2, Wf2t, 128, 384, 128);
    cvt_w<<<dim3(128), blk, 0, stream>>>(Wv,  Wvt,  128, 256, 128);
    cvt_w<<<dim3(384), blk, 0, stream>>>(Ws1, Ws1t, 256, 384, 256);
    cvt_w<<<dim3(576), blk, 0, stream>>>(Ws2, Ws2t, 384, 384, 384);

    // ---- P1: interaction MLP, 2 node chunks ----
    {
        const int NC1 = 16384;
        bf16* x1c = slotP;
        for (int n0 = 0; n0 < N; n0 += NC1) {
            mgemm<float, bf16, 1><<<dim3(NC1 / 128, 3), blk, 0, stream>>>(
                q + (size_t)n0 * 128, Wi1t, bi1, nullptr, x1c, NC1, 128, 384, 128);
            mgemm<bf16, bf16, 0><<<dim3(NC1 / 128, 3), blk, 0, stream>>>(
                x1c, Wi2t, bi2, nullptr, xb + (size_t)n0 * 384, NC1, 384, 384, 0);
        }
    }

    // ---- P2: zero accumulators (d_out) + deg ----
    zero_k<<<dim3(16384), blk, 0, stream>>>((float4*)d_out, (size_t)N * 512 / 4);
    zero_k<<<dim3(32), blk, 0, stream>>>((float4*)deg, (size_t)N / 4);

    // ---- P3: filter network + edge aggregation, 16 edge chunks ----
    {
        const int EC = 16384;
        bf16* filc = slotA;
        bf16* hf   = slotP;
        for (int e0 = 0; e0 < E; e0 += EC) {
            mgemm<float, bf16, 1><<<dim3(EC / 128, 1), blk, 0, stream>>>(
                rbf + (size_t)e0 * 20, Wf1t, bf1, nullptr, hf, EC, 32, 128, 20);
            mgemm<bf16, bf16, 2><<<dim3(EC / 128, 3), blk, 0, stream>>>(
                hf, Wf2t, bf2, cut + e0, filc, EC, 128, 384, 0);
            edge_agg<<<dim3(EC / 2), blk, 0, stream>>>(
                xb, filc, mu, ei, uv, outq, outmu, deg, e0, EC, E);
        }
    }

    // ---- P4: q_new / mu_new in place ----
    finalize_k<<<dim3(N * 128 / 256), blk, 0, stream>>>(q, mu, deg, outq, outmu, N);

    // ---- P5: mixing, 8 node chunks (xb dead; mix bufs alias slotB) ----
    {
        const int NC2 = 4096;
        float* mcat  = (float*)slotA;                                   // 12.58 MB
        bf16*  scin  = (bf16*)((char*)xb);                              // 2.1 MB
        float* inner = (float*)((char*)xb + (size_t)NC2 * 256 * 2);     // 2.1 MB
        bf16*  s1    = (bf16*)((char*)inner + (size_t)NC2 * 128 * 4);   // 3.1 MB
        bf16*  delta = (bf16*)((char*)s1 + (size_t)NC2 * 384 * 2);      // 3.1 MB
        for (int n0 = 0; n0 < N; n0 += NC2) {
            mgemm<float, float, 0><<<dim3(3 * NC2 / 128, 2), blk, 0, stream>>>(
                outmu + (size_t)n0 * 384, Wvt, nullptr, nullptr, mcat,
                3 * NC2, 128, 256, 128);
            mix_pre<<<dim3(NC2 * 128 / 256), blk, 0, stream>>>(
                mcat, outq + (size_t)n0 * 128, scin, inner, NC2);
            mgemm<bf16, bf16, 1><<<dim3(NC2 / 128, 3), blk, 0, stream>>>(
                scin, Ws1t, bs1, nullptr, s1, NC2, 256, 384, 0);
            mgemm<bf16, bf16, 0><<<dim3(NC2 / 128, 3), blk, 0, stream>>>(
                s1, Ws2t, bs2, nullptr, delta, NC2, 384, 384, 0);
            mix_post<<<dim3(NC2 * 128 / 256), blk, 0, stream>>>(
                delta, inner, mcat, outq, outmu, n0, NC2);
        }
    }
}

// Round 4
// 1359.508 us; speedup vs baseline: 1.4394x; 1.0176x over previous
//
#include <hip/hip_runtime.h>
#include <hip/hip_bf16.h>

typedef __hip_bfloat16 bf16;
typedef __attribute__((ext_vector_type(8))) short bf16x8;
typedef __attribute__((ext_vector_type(4))) short bf16x4v;
typedef __attribute__((ext_vector_type(4))) float f32x4;

__device__ __forceinline__ void gload_lds16(const void* g, void* l)
{
    __builtin_amdgcn_global_load_lds(
        (const __attribute__((address_space(1))) void*)g,
        (__attribute__((address_space(3))) void*)l, 16, 0, 0);
}

// ---------------------------------------------------------------------------
// MFMA bf16 GEMM: C = epi(A @ Bt^T + bias)
//   A:  [M][K]  TA=bf16: row stride K (K%32==0), staged via global_load_lds.
//               TA=float: row stride ka; logical K%32==0, cols k>=ka are 0.
//   Bt: [N][K]  bf16 (weights pre-transposed), row stride K.
//   C:  [M][N]  (bf16 or float), M%128==0, N%128==0.
// 256 threads = 4 waves (2x2), each wave 64x64 via 4x4 MFMA 16x16x32.
// EPI: 0 none, 1 SiLU, 2 rowscale (post-bias multiply by rowscale[m])
// ---------------------------------------------------------------------------
template<typename TA, typename TC, int EPI>
__global__ __launch_bounds__(256) void mgemm(
    const TA* __restrict__ A, const bf16* __restrict__ Bt,
    const float* __restrict__ bias, const float* __restrict__ rowscale,
    TC* __restrict__ C, int M, int K, int N, int ka)
{
    __shared__ __align__(16) bf16 As[128 * 32];
    __shared__ __align__(16) bf16 Bs[128 * 32];
    const int tid = threadIdx.x;
    const int lane = tid & 63;
    const int wave = tid >> 6;
    const int col16 = lane & 15;
    const int quad = lane >> 4;
    const int wm = (wave & 1) * 64;
    const int wn = (wave >> 1) * 64;
    const size_t m0 = (size_t)blockIdx.x * 128;
    const int n0 = blockIdx.y * 128;

    f32x4 acc[4][4];
#pragma unroll
    for (int i = 0; i < 4; ++i)
#pragma unroll
        for (int j = 0; j < 4; ++j) acc[i][j] = (f32x4){0.f, 0.f, 0.f, 0.f};

    const int rbase = wave * 32;          // staging rows for this wave
    const int srow = lane >> 2;           // 0..15
    const int schk = lane & 3;            // 16B chunk within 64B row

    for (int k0 = 0; k0 < K; k0 += 32) {
        // ---- stage A tile [128 rows][32 k] ----
        if constexpr (sizeof(TA) == 2) {
            const bf16* g0 = (const bf16*)A + (m0 + rbase + srow) * (size_t)K + k0 + schk * 8;
            gload_lds16(g0, As + rbase * 32);
            gload_lds16(g0 + 16 * (size_t)K, As + (rbase + 16) * 32);
        } else {
#pragma unroll
            for (int r = 0; r < 4; ++r) {
                int p = tid + 256 * r;
                int row = p >> 3, kp = p & 7;
                int kg = k0 + kp * 4;
                float4 v = make_float4(0.f, 0.f, 0.f, 0.f);
                if (kg < ka) v = *(const float4*)((const float*)A + (m0 + row) * (size_t)ka + kg);
                bf16 t[4] = {__float2bfloat16(v.x), __float2bfloat16(v.y),
                             __float2bfloat16(v.z), __float2bfloat16(v.w)};
                *(bf16x4v*)(As + row * 32 + kp * 4) = *(const bf16x4v*)t;
            }
        }
        // ---- stage B tile [128 n][32 k] via global_load_lds ----
        {
            const bf16* g0 = Bt + (size_t)(n0 + rbase + srow) * K + k0 + schk * 8;
            gload_lds16(g0, Bs + rbase * 32);
            gload_lds16(g0 + 16 * (size_t)K, Bs + (rbase + 16) * 32);
        }
        __syncthreads();

        bf16x8 a[4], b[4];
#pragma unroll
        for (int i = 0; i < 4; ++i)
            a[i] = *(const bf16x8*)(As + (wm + i * 16 + col16) * 32 + quad * 8);
#pragma unroll
        for (int j = 0; j < 4; ++j)
            b[j] = *(const bf16x8*)(Bs + (wn + j * 16 + col16) * 32 + quad * 8);
#pragma unroll
        for (int i = 0; i < 4; ++i)
#pragma unroll
            for (int j = 0; j < 4; ++j)
                acc[i][j] = __builtin_amdgcn_mfma_f32_16x16x32_bf16(a[i], b[j], acc[i][j], 0, 0, 0);
        __syncthreads();
    }

    // ---- epilogue: C[m0+wm+i*16+quad*4+r][n0+wn+j*16+col16] ----
#pragma unroll
    for (int j = 0; j < 4; ++j) {
        int col = n0 + wn + j * 16 + col16;
        float bv = bias ? bias[col] : 0.f;
#pragma unroll
        for (int i = 0; i < 4; ++i) {
#pragma unroll
            for (int r = 0; r < 4; ++r) {
                size_t row = m0 + wm + i * 16 + quad * 4 + r;
                float v = acc[i][j][r] + bv;
                if (EPI == 1) v = v / (1.f + expf(-v));
                if (EPI == 2) v *= rowscale[row];
                if constexpr (sizeof(TC) == 2)
                    ((bf16*)C)[row * (size_t)N + col] = __float2bfloat16(v);
                else
                    ((float*)C)[row * (size_t)N + col] = v;
            }
        }
    }
}

// Fused weight transpose+convert for all 7 weights.
struct CvtArgs {
    const float* in[7];
    bf16* out[7];
    int K[7], Nc[7], Kp[7];
    int cum[8];
};
__global__ __launch_bounds__(256) void cvt_all(CvtArgs a)
{
    int i = blockIdx.x * 256 + threadIdx.x;
#pragma unroll
    for (int s = 0; s < 7; ++s) {
        if (i >= a.cum[s] && i < a.cum[s + 1]) {
            int j = i - a.cum[s];
            int n = j / a.Kp[s], k = j - n * a.Kp[s];
            a.out[s][j] = __float2bfloat16(
                k < a.K[s] ? a.in[s][(size_t)k * a.Nc[s] + n] : 0.f);
        }
    }
}

__global__ __launch_bounds__(256) void zero_k(float4* __restrict__ p, size_t n4)
{
    size_t i = (size_t)blockIdx.x * 256 + threadIdx.x;
    if (i < n4) p[i] = make_float4(0.f, 0.f, 0.f, 0.f);
}

// One wave per edge; lane handles channels 2*lane, 2*lane+1.
__global__ __launch_bounds__(256) void edge_agg(
    const bf16* __restrict__ x, const bf16* __restrict__ filt,
    const float* __restrict__ mu, const int* __restrict__ ei,
    const float* __restrict__ uv,
    float* __restrict__ outq, float* __restrict__ outmu,
    float* __restrict__ deg, int e0, int EC, int E)
{
    int le = blockIdx.x * 4 + (threadIdx.x >> 6);
    if (le >= EC) return;
    int lane = threadIdx.x & 63;
    int e = e0 + le;
    int tgt = ei[e];
    int src = ei[E + e];
    int h = lane * 2;

    const bf16* fp = filt + (size_t)le * 384;
    const bf16* xp = x + (size_t)src * 384;
    const float* mus = mu + (size_t)src * 384;

    __hip_bfloat162 fq2 = *(const __hip_bfloat162*)(fp + h);
    __hip_bfloat162 fr2 = *(const __hip_bfloat162*)(fp + 128 + h);
    __hip_bfloat162 fm2 = *(const __hip_bfloat162*)(fp + 256 + h);
    __hip_bfloat162 xq2 = *(const __hip_bfloat162*)(xp + h);
    __hip_bfloat162 xr2 = *(const __hip_bfloat162*)(xp + 128 + h);
    __hip_bfloat162 xm2 = *(const __hip_bfloat162*)(xp + 256 + h);

    float xq0 = __bfloat162float(xq2.x) * __bfloat162float(fq2.x);
    float xq1 = __bfloat162float(xq2.y) * __bfloat162float(fq2.y);
    float xr0 = __bfloat162float(xr2.x) * __bfloat162float(fr2.x);
    float xr1 = __bfloat162float(xr2.y) * __bfloat162float(fr2.y);
    float xm0 = __bfloat162float(xm2.x) * __bfloat162float(fm2.x);
    float xm1 = __bfloat162float(xm2.y) * __bfloat162float(fm2.y);

    float u0 = uv[e * 3 + 0];
    float u1 = uv[e * 3 + 1];
    float u2 = uv[e * 3 + 2];
    float2 m0v = *(const float2*)(mus + h);
    float2 m1v = *(const float2*)(mus + 128 + h);
    float2 m2v = *(const float2*)(mus + 256 + h);

    float* oq = outq + (size_t)tgt * 128 + h;
    atomicAdd(oq, xq0);
    atomicAdd(oq + 1, xq1);
    float* om = outmu + (size_t)tgt * 384 + h;
    atomicAdd(om,           fmaf(u0, xr0, m0v.x * xm0));
    atomicAdd(om + 1,       fmaf(u0, xr1, m0v.y * xm1));
    atomicAdd(om + 128,     fmaf(u1, xr0, m1v.x * xm0));
    atomicAdd(om + 129,     fmaf(u1, xr1, m1v.y * xm1));
    atomicAdd(om + 256,     fmaf(u2, xr0, m2v.x * xm0));
    atomicAdd(om + 257,     fmaf(u2, xr1, m2v.y * xm1));
    if (lane == 0) atomicAdd(&deg[tgt], 1.f);
}

// In place: outq = q + outq/deg ; outmu = mu + outmu/deg
__global__ __launch_bounds__(256) void finalize_k(
    const float* __restrict__ q, const float* __restrict__ mu,
    const float* __restrict__ deg,
    float* __restrict__ outq, float* __restrict__ outmu, int N)
{
    int i = blockIdx.x * 256 + threadIdx.x;
    if (i >= N * 128) return;
    int n = i >> 7;
    int h = i & 127;
    float inv = 1.f / fmaxf(deg[n], 1.f);
    outq[i] = q[i] + outq[i] * inv;
    size_t b = (size_t)n * 384 + h;
    outmu[b]       = mu[b]       + outmu[b]       * inv;
    outmu[b + 128] = mu[b + 128] + outmu[b + 128] * inv;
    outmu[b + 256] = mu[b + 256] + outmu[b + 256] * inv;
}

// mcat bf16 [3N][256]: scin=[q|norm] bf16, inner f32
__global__ __launch_bounds__(256) void mix_pre(
    const bf16* __restrict__ mcat, const float* __restrict__ outq,
    bf16* __restrict__ scin, float* __restrict__ inner, int N)
{
    int i = blockIdx.x * 256 + threadIdx.x;
    if (i >= N * 128) return;
    int n = i >> 7;
    int h = i & 127;
    size_t r = (size_t)n * 768;
    float v0 = __bfloat162float(mcat[r + h]);
    float w0 = __bfloat162float(mcat[r + 128 + h]);
    float v1 = __bfloat162float(mcat[r + 256 + h]);
    float w1 = __bfloat162float(mcat[r + 384 + h]);
    float v2 = __bfloat162float(mcat[r + 512 + h]);
    float w2 = __bfloat162float(mcat[r + 640 + h]);
    float nrm = sqrtf(v0 * v0 + v1 * v1 + v2 * v2 + 1e-8f);
    inner[i] = v0 * w0 + v1 * w1 + v2 * w2;
    scin[(size_t)n * 256 + h] = __float2bfloat16(outq[i]);
    scin[(size_t)n * 256 + 128 + h] = __float2bfloat16(nrm);
}

// q += dq + dqmu*inner ; mu += mu_w * dmu_scale (mu_w from mcat cols 128:256)
__global__ __launch_bounds__(256) void mix_post(
    const bf16* __restrict__ delta, const float* __restrict__ inner,
    const bf16* __restrict__ mcat,
    float* __restrict__ outq, float* __restrict__ outmu, int N)
{
    int i = blockIdx.x * 256 + threadIdx.x;
    if (i >= N * 128) return;
    int n = i >> 7;
    int h = i & 127;
    size_t dr = (size_t)n * 384;
    float dq  = __bfloat162float(delta[dr + h]);
    float dsc = __bfloat162float(delta[dr + 128 + h]);
    float dqm = __bfloat162float(delta[dr + 256 + h]);
    outq[i] += dq + dqm * inner[i];
    size_t r = (size_t)n * 768;
    size_t mb = (size_t)n * 384 + h;
    outmu[mb]       += __bfloat162float(mcat[r + 128 + h]) * dsc;
    outmu[mb + 128] += __bfloat162float(mcat[r + 384 + h]) * dsc;
    outmu[mb + 256] += __bfloat162float(mcat[r + 640 + h]) * dsc;
}

extern "C" void kernel_launch(void* const* d_in, const int* in_sizes, int n_in,
                              void* d_out, int out_size, void* d_ws, size_t ws_size,
                              hipStream_t stream)
{
    const float* q   = (const float*)d_in[0];
    const float* mu  = (const float*)d_in[1];
    const int*   ei  = (const int*)d_in[2];
    const float* rbf = (const float*)d_in[3];
    const float* uv  = (const float*)d_in[4];
    const float* cut = (const float*)d_in[5];
    const float* Wi1 = (const float*)d_in[6];
    const float* bi1 = (const float*)d_in[7];
    const float* Wi2 = (const float*)d_in[8];
    const float* bi2 = (const float*)d_in[9];
    const float* Wf1 = (const float*)d_in[10];
    const float* bf1 = (const float*)d_in[11];
    const float* Wf2 = (const float*)d_in[12];
    const float* bf2 = (const float*)d_in[13];
    const float* Wv  = (const float*)d_in[14];
    const float* Ws1 = (const float*)d_in[15];
    const float* bs1 = (const float*)d_in[16];
    const float* Ws2 = (const float*)d_in[17];
    const float* bs2 = (const float*)d_in[18];

    const int H = 128;
    const int N = in_sizes[0] / H;   // 32768
    const int E = in_sizes[5];       // 262144
    const int EH = E / 2;            // edge half-chunk
    (void)n_in; (void)out_size;

    // ---- workspace layout (ws_size = 256 MiB measured; need 153.2 MiB) ----
    char* ws = (char*)d_ws;
    const size_t SZ_XB  = (size_t)N * 384 * 2;    //  25.17 MB
    const size_t SZ_FIL = (size_t)EH * 384 * 2;   // 100.66 MB
    const size_t SZ_HF  = (size_t)EH * 128 * 2;   //  33.55 MB
    const size_t TAIL   = SZ_XB + SZ_FIL + SZ_HF; // 159,383,552 B
    bf16*  xb   = (bf16*)ws;                      // [P1..P3]
    bf16*  filc = (bf16*)(ws + SZ_XB);            // [P3]; x1 alias in P1
    bf16*  hf   = (bf16*)(ws + SZ_XB + SZ_FIL);   // [P3]
    float* deg  = (float*)(ws + TAIL);
    bf16*  wts  = (bf16*)(ws + TAIL + (size_t)N * 4);
    // P5 aliases (everything pre-P5 dead): 134.2 MB < TAIL
    bf16*  mcat  = (bf16*)ws;                                  // N*768*2
    bf16*  scin  = (bf16*)(ws + (size_t)N * 768 * 2);          // N*256*2
    float* inner = (float*)(ws + (size_t)N * (768 + 256) * 2); // N*128*4
    bf16*  s1    = (bf16*)((char*)inner + (size_t)N * 128 * 4);
    bf16*  delta = (bf16*)((char*)s1 + (size_t)N * 384 * 2);
    if (ws_size < TAIL + (size_t)N * 4 + 1100000) return;

    bf16* Wi1t = wts;             // [384][128]
    bf16* Wi2t = Wi1t + 49152;    // [384][384]
    bf16* Wf1t = Wi2t + 147456;   // [128][32]
    bf16* Wf2t = Wf1t + 4096;     // [384][128]
    bf16* Wvt  = Wf2t + 49152;    // [256][128]
    bf16* Ws1t = Wvt  + 32768;    // [384][256]
    bf16* Ws2t = Ws1t + 98304;    // [384][384]

    float* outq  = (float*)d_out;
    float* outmu = outq + (size_t)N * 128;

    dim3 blk(256);

    // ---- P0: all weights -> bf16 transposed (one dispatch) ----
    {
        CvtArgs a;
        const float* wi[7] = {Wi1, Wi2, Wf1, Wf2, Wv, Ws1, Ws2};
        bf16* wo[7] = {Wi1t, Wi2t, Wf1t, Wf2t, Wvt, Ws1t, Ws2t};
        int K[7]  = {128, 384, 20, 128, 128, 256, 384};
        int Nc[7] = {384, 384, 128, 384, 256, 384, 384};
        int Kp[7] = {128, 384, 32, 128, 128, 256, 384};
        int c = 0;
        for (int s = 0; s < 7; ++s) {
            a.in[s] = wi[s]; a.out[s] = wo[s];
            a.K[s] = K[s]; a.Nc[s] = Nc[s]; a.Kp[s] = Kp[s];
            a.cum[s] = c; c += Nc[s] * Kp[s];
        }
        a.cum[7] = c;
        cvt_all<<<dim3((c + 255) / 256), blk, 0, stream>>>(a);
    }

    // ---- P1: interaction MLP (full) ----
    {
        bf16* x1 = filc;   // scratch
        mgemm<float, bf16, 1><<<dim3(N / 128, 3), blk, 0, stream>>>(
            q, Wi1t, bi1, nullptr, x1, N, 128, 384, 128);
        mgemm<bf16, bf16, 0><<<dim3(N / 128, 3), blk, 0, stream>>>(
            x1, Wi2t, bi2, nullptr, xb, N, 384, 384, 0);
    }

    // ---- P2: zero accumulators (d_out) + deg ----
    zero_k<<<dim3(16384), blk, 0, stream>>>((float4*)d_out, (size_t)N * 512 / 4);
    zero_k<<<dim3(32), blk, 0, stream>>>((float4*)deg, (size_t)N / 4);

    // ---- P3: filter network + edge aggregation, 2 half-chunks ----
    for (int e0 = 0; e0 < E; e0 += EH) {
        mgemm<float, bf16, 1><<<dim3(EH / 128, 1), blk, 0, stream>>>(
            rbf + (size_t)e0 * 20, Wf1t, bf1, nullptr, hf, EH, 32, 128, 20);
        mgemm<bf16, bf16, 2><<<dim3(EH / 128, 3), blk, 0, stream>>>(
            hf, Wf2t, bf2, cut + e0, filc, EH, 128, 384, 0);
        edge_agg<<<dim3(EH / 4), blk, 0, stream>>>(
            xb, filc, mu, ei, uv, outq, outmu, deg, e0, EH, E);
    }

    // ---- P4: q_new / mu_new in place ----
    finalize_k<<<dim3(N * 128 / 256), blk, 0, stream>>>(q, mu, deg, outq, outmu, N);

    // ---- P5: mixing (full) ----
    mgemm<float, bf16, 0><<<dim3(3 * N / 128, 2), blk, 0, stream>>>(
        outmu, Wvt, nullptr, nullptr, mcat, 3 * N, 128, 256, 128);
    mix_pre<<<dim3(N * 128 / 256), blk, 0, stream>>>(mcat, outq, scin, inner, N);
    mgemm<bf16, bf16, 1><<<dim3(N / 128, 3), blk, 0, stream>>>(
        scin, Ws1t, bs1, nullptr, s1, N, 256, 384, 0);
    mgemm<bf16, bf16, 0><<<dim3(N / 128, 3), blk, 0, stream>>>(
        s1, Ws2t, bs2, nullptr, delta, N, 384, 384, 0);
    mix_post<<<dim3(N * 128 / 256), blk, 0, stream>>>(delta, inner, mcat,
                                                      outq, outmu, N);
}

// Round 6
// 678.021 us; speedup vs baseline: 2.8862x; 2.0051x over previous
//
#include <hip/hip_runtime.h>
#include <hip/hip_bf16.h>

typedef __hip_bfloat16 bf16;
typedef __attribute__((ext_vector_type(8))) short bf16x8;
typedef __attribute__((ext_vector_type(4))) short bf16x4v;
typedef __attribute__((ext_vector_type(4))) float f32x4;

__device__ __forceinline__ void gload_lds16(const void* g, void* l)
{
    __builtin_amdgcn_global_load_lds(
        (const __attribute__((address_space(1))) void*)g,
        (__attribute__((address_space(3))) void*)l, 16, 0, 0);
}

// ---------------------------------------------------------------------------
// MFMA bf16 GEMM: C = epi(A @ Bt^T + bias)
//   A:  [M][K]  TA=bf16: row stride K (K%32==0), staged via global_load_lds.
//               TA=float: row stride ka; logical K%32==0, cols k>=ka are 0;
//               optional row gather via Aperm.
//   Bt: [N][K]  bf16 (weights pre-transposed), row stride K.
//   C:  [M][N]  (bf16 or float), M%128==0, N%128==0.
// 256 threads = 4 waves (2x2), each wave 64x64 via 4x4 MFMA 16x16x32.
// EPI: 0 none, 1 SiLU, 2 rowscale (post-bias multiply by rowscale[m])
// ---------------------------------------------------------------------------
template<typename TA, typename TC, int EPI>
__global__ __launch_bounds__(256) void mgemm(
    const TA* __restrict__ A, const bf16* __restrict__ Bt,
    const float* __restrict__ bias, const float* __restrict__ rowscale,
    TC* __restrict__ C, int M, int K, int N, int ka,
    const int* __restrict__ Aperm)
{
    __shared__ __align__(16) bf16 As[128 * 32];
    __shared__ __align__(16) bf16 Bs[128 * 32];
    const int tid = threadIdx.x;
    const int lane = tid & 63;
    const int wave = tid >> 6;
    const int col16 = lane & 15;
    const int quad = lane >> 4;
    const int wm = (wave & 1) * 64;
    const int wn = (wave >> 1) * 64;
    const size_t m0 = (size_t)blockIdx.x * 128;
    const int n0 = blockIdx.y * 128;

    f32x4 acc[4][4];
#pragma unroll
    for (int i = 0; i < 4; ++i)
#pragma unroll
        for (int j = 0; j < 4; ++j) acc[i][j] = (f32x4){0.f, 0.f, 0.f, 0.f};

    const int rbase = wave * 32;
    const int srow = lane >> 2;
    const int schk = lane & 3;

    for (int k0 = 0; k0 < K; k0 += 32) {
        if constexpr (sizeof(TA) == 2) {
            const bf16* g0 = (const bf16*)A + (m0 + rbase + srow) * (size_t)K + k0 + schk * 8;
            gload_lds16(g0, As + rbase * 32);
            gload_lds16(g0 + 16 * (size_t)K, As + (rbase + 16) * 32);
        } else {
#pragma unroll
            for (int r = 0; r < 4; ++r) {
                int p = tid + 256 * r;
                int row = p >> 3, kp = p & 7;
                int kg = k0 + kp * 4;
                size_t arow = Aperm ? (size_t)Aperm[m0 + row] : (m0 + row);
                float4 v = make_float4(0.f, 0.f, 0.f, 0.f);
                if (kg < ka) v = *(const float4*)((const float*)A + arow * (size_t)ka + kg);
                bf16 t[4] = {__float2bfloat16(v.x), __float2bfloat16(v.y),
                             __float2bfloat16(v.z), __float2bfloat16(v.w)};
                *(bf16x4v*)(As + row * 32 + kp * 4) = *(const bf16x4v*)t;
            }
        }
        {
            const bf16* g0 = Bt + (size_t)(n0 + rbase + srow) * K + k0 + schk * 8;
            gload_lds16(g0, Bs + rbase * 32);
            gload_lds16(g0 + 16 * (size_t)K, Bs + (rbase + 16) * 32);
        }
        __syncthreads();

        bf16x8 a[4], b[4];
#pragma unroll
        for (int i = 0; i < 4; ++i)
            a[i] = *(const bf16x8*)(As + (wm + i * 16 + col16) * 32 + quad * 8);
#pragma unroll
        for (int j = 0; j < 4; ++j)
            b[j] = *(const bf16x8*)(Bs + (wn + j * 16 + col16) * 32 + quad * 8);
#pragma unroll
        for (int i = 0; i < 4; ++i)
#pragma unroll
            for (int j = 0; j < 4; ++j)
                acc[i][j] = __builtin_amdgcn_mfma_f32_16x16x32_bf16(a[i], b[j], acc[i][j], 0, 0, 0);
        __syncthreads();
    }

#pragma unroll
    for (int j = 0; j < 4; ++j) {
        int col = n0 + wn + j * 16 + col16;
        float bv = bias ? bias[col] : 0.f;
#pragma unroll
        for (int i = 0; i < 4; ++i) {
#pragma unroll
            for (int r = 0; r < 4; ++r) {
                size_t row = m0 + wm + i * 16 + quad * 4 + r;
                float v = acc[i][j][r] + bv;
                if (EPI == 1) v = v / (1.f + expf(-v));
                if (EPI == 2) v *= rowscale[row];
                if constexpr (sizeof(TC) == 2)
                    ((bf16*)C)[row * (size_t)N + col] = __float2bfloat16(v);
                else
                    ((float*)C)[row * (size_t)N + col] = v;
            }
        }
    }
}

// Fused weight transpose+convert for all 7 weights.
struct CvtArgs {
    const float* in[7];
    bf16* out[7];
    int K[7], Nc[7], Kp[7];
    int cum[8];
};
__global__ __launch_bounds__(256) void cvt_all(CvtArgs a)
{
    int i = blockIdx.x * 256 + threadIdx.x;
#pragma unroll
    for (int s = 0; s < 7; ++s) {
        if (i >= a.cum[s] && i < a.cum[s + 1]) {
            int j = i - a.cum[s];
            int n = j / a.Kp[s], k = j - n * a.Kp[s];
            a.out[s][j] = __float2bfloat16(
                k < a.K[s] ? a.in[s][(size_t)k * a.Nc[s] + n] : 0.f);
        }
    }
}

// fp32 -> bf16 bulk convert (4 elements/thread)
__global__ __launch_bounds__(256) void cvt_bf16(
    const float4* __restrict__ in, bf16* __restrict__ out, size_t n4)
{
    size_t i = (size_t)blockIdx.x * 256 + threadIdx.x;
    if (i >= n4) return;
    float4 v = in[i];
    bf16 t[4] = {__float2bfloat16(v.x), __float2bfloat16(v.y),
                 __float2bfloat16(v.z), __float2bfloat16(v.w)};
    *(bf16x4v*)(out + i * 4) = *(const bf16x4v*)t;
}

__global__ __launch_bounds__(256) void zero_k(float4* __restrict__ p, size_t n4)
{
    size_t i = (size_t)blockIdx.x * 256 + threadIdx.x;
    if (i < n4) p[i] = make_float4(0.f, 0.f, 0.f, 0.f);
}

// ---- counting sort by target ----
__global__ __launch_bounds__(256) void hist_k(
    const int* __restrict__ ei, int* __restrict__ hist, int E)
{
    int e = blockIdx.x * 256 + threadIdx.x;
    if (e < E) atomicAdd(&hist[ei[e]], 1);
}

// Single block, 256 threads, each handles 128 targets. N=32768, halves at 16384.
__global__ __launch_bounds__(256) void scan_k(
    const int* __restrict__ hist, int* __restrict__ off,
    int* __restrict__ cursor, int N, int SLOT1)
{
    __shared__ int ps[257];
    int tid = threadIdx.x;
    int base = tid * 128;
    int s = 0;
    for (int i = 0; i < 128; ++i) s += hist[base + i];
    ps[tid] = s;
    __syncthreads();
    if (tid == 0) {
        int run = 0;
        for (int i = 0; i < 256; ++i) { int t = ps[i]; ps[i] = run; run += t; }
        ps[256] = run;
    }
    __syncthreads();
    int T0 = ps[128];     // edges with tgt < 16384
    int run = ps[tid];
    for (int i = 0; i < 128; ++i) {
        int n = base + i;
        int o = (n < 16384) ? run : SLOT1 + run - T0;
        off[n] = o; cursor[n] = o;
        run += hist[n];
    }
    if (tid == 255) off[N] = SLOT1 + run - T0;
}

__global__ __launch_bounds__(256) void scatter_k(
    const int* __restrict__ ei, const float* __restrict__ uv,
    const float* __restrict__ cut, int* __restrict__ cursor,
    int* __restrict__ perm, int* __restrict__ srcp,
    float* __restrict__ cutp, float* __restrict__ uvp, int E)
{
    int e = blockIdx.x * 256 + threadIdx.x;
    if (e >= E) return;
    int tgt = ei[e];
    int pos = atomicAdd(&cursor[tgt], 1);
    perm[pos] = e;
    srcp[pos] = ei[E + e];
    cutp[pos] = cut[e];
    uvp[pos * 3 + 0] = uv[e * 3 + 0];
    uvp[pos * 3 + 1] = uv[e * 3 + 1];
    uvp[pos * 3 + 2] = uv[e * 3 + 2];
}

// ---- segmented edge reduction: one wave per target, no atomics ----
// filt is chunk-local (row p-base). Segment length from hist (NOT off[n+1]:
// region boundary at n=16383 has slack; off[n+1] would overrun into it).
// Fuses residual + /deg (finalize).
__global__ __launch_bounds__(256) void edge_seg(
    const bf16* __restrict__ x, const bf16* __restrict__ filt,
    const bf16* __restrict__ mub, const int* __restrict__ srcp,
    const float* __restrict__ uvp, const int* __restrict__ off,
    const int* __restrict__ hist,
    const float* __restrict__ q, const float* __restrict__ mu,
    float* __restrict__ outq, float* __restrict__ outmu,
    int t0, int tcount, int base)
{
    int t = blockIdx.x * 4 + (threadIdx.x >> 6);
    if (t >= tcount) return;
    int n = t0 + t;
    int lane = threadIdx.x & 63;
    int h = lane * 2;
    int p0 = off[n];
    int cnt = hist[n];
    int p1 = p0 + cnt;

    float aq0 = 0.f, aq1 = 0.f;
    float am00 = 0.f, am01 = 0.f, am10 = 0.f, am11 = 0.f, am20 = 0.f, am21 = 0.f;

    for (int p = p0; p < p1; ++p) {
        const bf16* fp_ = filt + (size_t)(p - base) * 384;
        int src = srcp[p];
        const bf16* xp = x + (size_t)src * 384;
        const bf16* mp = mub + (size_t)src * 384;

        __hip_bfloat162 fq2 = *(const __hip_bfloat162*)(fp_ + h);
        __hip_bfloat162 fr2 = *(const __hip_bfloat162*)(fp_ + 128 + h);
        __hip_bfloat162 fm2 = *(const __hip_bfloat162*)(fp_ + 256 + h);
        __hip_bfloat162 xq2 = *(const __hip_bfloat162*)(xp + h);
        __hip_bfloat162 xr2 = *(const __hip_bfloat162*)(xp + 128 + h);
        __hip_bfloat162 xm2 = *(const __hip_bfloat162*)(xp + 256 + h);
        __hip_bfloat162 m02 = *(const __hip_bfloat162*)(mp + h);
        __hip_bfloat162 m12 = *(const __hip_bfloat162*)(mp + 128 + h);
        __hip_bfloat162 m22 = *(const __hip_bfloat162*)(mp + 256 + h);
        float u0 = uvp[p * 3 + 0];
        float u1 = uvp[p * 3 + 1];
        float u2 = uvp[p * 3 + 2];

        float xq0 = __bfloat162float(xq2.x) * __bfloat162float(fq2.x);
        float xq1 = __bfloat162float(xq2.y) * __bfloat162float(fq2.y);
        float xr0 = __bfloat162float(xr2.x) * __bfloat162float(fr2.x);
        float xr1 = __bfloat162float(xr2.y) * __bfloat162float(fr2.y);
        float xm0 = __bfloat162float(xm2.x) * __bfloat162float(fm2.x);
        float xm1 = __bfloat162float(xm2.y) * __bfloat162float(fm2.y);

        aq0 += xq0; aq1 += xq1;
        am00 += fmaf(u0, xr0, __bfloat162float(m02.x) * xm0);
        am01 += fmaf(u0, xr1, __bfloat162float(m02.y) * xm1);
        am10 += fmaf(u1, xr0, __bfloat162float(m12.x) * xm0);
        am11 += fmaf(u1, xr1, __bfloat162float(m12.y) * xm1);
        am20 += fmaf(u2, xr0, __bfloat162float(m22.x) * xm0);
        am21 += fmaf(u2, xr1, __bfloat162float(m22.y) * xm1);
    }

    float inv = 1.f / fmaxf((float)cnt, 1.f);
    size_t qb = (size_t)n * 128 + h;
    outq[qb]     = q[qb]     + aq0 * inv;
    outq[qb + 1] = q[qb + 1] + aq1 * inv;
    size_t mb = (size_t)n * 384 + h;
    outmu[mb]       = mu[mb]       + am00 * inv;
    outmu[mb + 1]   = mu[mb + 1]   + am01 * inv;
    outmu[mb + 128] = mu[mb + 128] + am10 * inv;
    outmu[mb + 129] = mu[mb + 129] + am11 * inv;
    outmu[mb + 256] = mu[mb + 256] + am20 * inv;
    outmu[mb + 257] = mu[mb + 257] + am21 * inv;
}

// mcat bf16 [3N][256]: scin=[q|norm] bf16, inner f32
__global__ __launch_bounds__(256) void mix_pre(
    const bf16* __restrict__ mcat, const float* __restrict__ outq,
    bf16* __restrict__ scin, float* __restrict__ inner, int N)
{
    int i = blockIdx.x * 256 + threadIdx.x;
    if (i >= N * 128) return;
    int n = i >> 7;
    int h = i & 127;
    size_t r = (size_t)n * 768;
    float v0 = __bfloat162float(mcat[r + h]);
    float w0 = __bfloat162float(mcat[r + 128 + h]);
    float v1 = __bfloat162float(mcat[r + 256 + h]);
    float w1 = __bfloat162float(mcat[r + 384 + h]);
    float v2 = __bfloat162float(mcat[r + 512 + h]);
    float w2 = __bfloat162float(mcat[r + 640 + h]);
    float nrm = sqrtf(v0 * v0 + v1 * v1 + v2 * v2 + 1e-8f);
    inner[i] = v0 * w0 + v1 * w1 + v2 * w2;
    scin[(size_t)n * 256 + h] = __float2bfloat16(outq[i]);
    scin[(size_t)n * 256 + 128 + h] = __float2bfloat16(nrm);
}

// q += dq + dqmu*inner ; mu += mu_w * dmu_scale (mu_w from mcat cols 128:256)
__global__ __launch_bounds__(256) void mix_post(
    const bf16* __restrict__ delta, const float* __restrict__ inner,
    const bf16* __restrict__ mcat,
    float* __restrict__ outq, float* __restrict__ outmu, int N)
{
    int i = blockIdx.x * 256 + threadIdx.x;
    if (i >= N * 128) return;
    int n = i >> 7;
    int h = i & 127;
    size_t dr = (size_t)n * 384;
    float dq  = __bfloat162float(delta[dr + h]);
    float dsc = __bfloat162float(delta[dr + 128 + h]);
    float dqm = __bfloat162float(delta[dr + 256 + h]);
    outq[i] += dq + dqm * inner[i];
    size_t r = (size_t)n * 768;
    size_t mb = (size_t)n * 384 + h;
    outmu[mb]       += __bfloat162float(mcat[r + 128 + h]) * dsc;
    outmu[mb + 128] += __bfloat162float(mcat[r + 384 + h]) * dsc;
    outmu[mb + 256] += __bfloat162float(mcat[r + 640 + h]) * dsc;
}

extern "C" void kernel_launch(void* const* d_in, const int* in_sizes, int n_in,
                              void* d_out, int out_size, void* d_ws, size_t ws_size,
                              hipStream_t stream)
{
    const float* q   = (const float*)d_in[0];
    const float* mu  = (const float*)d_in[1];
    const int*   ei  = (const int*)d_in[2];
    const float* rbf = (const float*)d_in[3];
    const float* uv  = (const float*)d_in[4];
    const float* cut = (const float*)d_in[5];
    const float* Wi1 = (const float*)d_in[6];
    const float* bi1 = (const float*)d_in[7];
    const float* Wi2 = (const float*)d_in[8];
    const float* bi2 = (const float*)d_in[9];
    const float* Wf1 = (const float*)d_in[10];
    const float* bf1 = (const float*)d_in[11];
    const float* Wf2 = (const float*)d_in[12];
    const float* bf2 = (const float*)d_in[13];
    const float* Wv  = (const float*)d_in[14];
    const float* Ws1 = (const float*)d_in[15];
    const float* bs1 = (const float*)d_in[16];
    const float* Ws2 = (const float*)d_in[17];
    const float* bs2 = (const float*)d_in[18];

    const int H = 128;
    const int N = in_sizes[0] / H;   // 32768
    const int E = in_sizes[5];       // 262144
    const int SLOT1 = E / 2 + 4096;  // 135168, %128==0; fixed chunk-1 base
    (void)n_in; (void)out_size;

    // ---- workspace layout (~197 MB of the 256 MiB pool) ----
    char* ws = (char*)d_ws;
    size_t o = 0;
    auto take = [&](size_t b) { char* p = ws + o; o += (b + 255) & ~(size_t)255; return p; };
    bf16*  xb     = (bf16*)take((size_t)N * 384 * 2);        // 25.2 MB [P1..edge]
    bf16*  mub    = (bf16*)take((size_t)N * 384 * 2);        // 25.2 MB [edge]
    bf16*  filc   = (bf16*)take((size_t)SLOT1 * 384 * 2);    // 103.8 MB [P3]; x1 alias P1
    bf16*  hf     = (bf16*)take((size_t)SLOT1 * 128 * 2);    // 34.6 MB [P3]
    int*   perm   = (int*)take((size_t)2 * SLOT1 * 4);
    int*   srcp   = (int*)take((size_t)2 * SLOT1 * 4);
    float* cutp   = (float*)take((size_t)2 * SLOT1 * 4);
    float* uvp    = (float*)take((size_t)2 * SLOT1 * 12);
    int*   hist   = (int*)take((size_t)N * 4);
    int*   off    = (int*)take((size_t)(N + 64) * 4);
    int*   cursor = (int*)take((size_t)N * 4);
    bf16*  wts    = (bf16*)take(1100000);
    if (o > ws_size) return;
    // P5 aliases (xb/mub/filc dead): 134.3 MB
    bf16*  mcat  = (bf16*)ws;
    bf16*  scin  = mcat + (size_t)N * 768;
    float* inner = (float*)(scin + (size_t)N * 256);
    bf16*  s1    = (bf16*)(inner + (size_t)N * 128);
    bf16*  delta = s1 + (size_t)N * 384;

    bf16* Wi1t = wts;             // [384][128]
    bf16* Wi2t = Wi1t + 49152;    // [384][384]
    bf16* Wf1t = Wi2t + 147456;   // [128][32]
    bf16* Wf2t = Wf1t + 4096;     // [384][128]
    bf16* Wvt  = Wf2t + 49152;    // [256][128]
    bf16* Ws1t = Wvt  + 32768;    // [384][256]
    bf16* Ws2t = Ws1t + 98304;    // [384][384]

    float* outq  = (float*)d_out;
    float* outmu = outq + (size_t)N * 128;

    dim3 blk(256);

    // ---- P0: weights -> bf16 transposed; mu -> bf16 ----
    {
        CvtArgs a;
        const float* wi[7] = {Wi1, Wi2, Wf1, Wf2, Wv, Ws1, Ws2};
        bf16* wo[7] = {Wi1t, Wi2t, Wf1t, Wf2t, Wvt, Ws1t, Ws2t};
        int K[7]  = {128, 384, 20, 128, 128, 256, 384};
        int Nc[7] = {384, 384, 128, 384, 256, 384, 384};
        int Kp[7] = {128, 384, 32, 128, 128, 256, 384};
        int c = 0;
        for (int s = 0; s < 7; ++s) {
            a.in[s] = wi[s]; a.out[s] = wo[s];
            a.K[s] = K[s]; a.Nc[s] = Nc[s]; a.Kp[s] = Kp[s];
            a.cum[s] = c; c += Nc[s] * Kp[s];
        }
        a.cum[7] = c;
        cvt_all<<<dim3((c + 255) / 256), blk, 0, stream>>>(a);
        cvt_bf16<<<dim3((unsigned)((size_t)N * 384 / 4 / 256)), blk, 0, stream>>>(
            (const float4*)mu, mub, (size_t)N * 384 / 4);
    }

    // ---- P1: interaction MLP (full) ----
    {
        bf16* x1 = filc;   // scratch
        mgemm<float, bf16, 1><<<dim3(N / 128, 3), blk, 0, stream>>>(
            q, Wi1t, bi1, nullptr, x1, N, 128, 384, 128, nullptr);
        mgemm<bf16, bf16, 0><<<dim3(N / 128, 3), blk, 0, stream>>>(
            x1, Wi2t, bi2, nullptr, xb, N, 384, 384, 0, nullptr);
    }

    // ---- PS: counting sort by target ----
    zero_k<<<dim3((N / 4 + 255) / 256), blk, 0, stream>>>((float4*)hist, N / 4);
    zero_k<<<dim3(((2 * SLOT1) / 4 + 255) / 256), blk, 0, stream>>>(
        (float4*)perm, (size_t)2 * SLOT1 / 4);
    zero_k<<<dim3(((2 * SLOT1) / 4 + 255) / 256), blk, 0, stream>>>(
        (float4*)cutp, (size_t)2 * SLOT1 / 4);
    hist_k<<<dim3(E / 256), blk, 0, stream>>>(ei, hist, E);
    scan_k<<<dim3(1), blk, 0, stream>>>(hist, off, cursor, N, SLOT1);
    scatter_k<<<dim3(E / 256), blk, 0, stream>>>(ei, uv, cut, cursor,
                                                 perm, srcp, cutp, uvp, E);

    // ---- P3: filter GEMMs (sorted order) + segmented edge reduce, 2 chunks ----
    for (int c = 0; c < 2; ++c) {
        int base = c * SLOT1;
        mgemm<float, bf16, 1><<<dim3(SLOT1 / 128, 1), blk, 0, stream>>>(
            rbf, Wf1t, bf1, nullptr, hf, SLOT1, 32, 128, 20, perm + base);
        mgemm<bf16, bf16, 2><<<dim3(SLOT1 / 128, 3), blk, 0, stream>>>(
            hf, Wf2t, bf2, cutp + base, filc, SLOT1, 128, 384, 0, nullptr);
        edge_seg<<<dim3(16384 / 4), blk, 0, stream>>>(
            xb, filc, mub, srcp, uvp, off, hist, q, mu, outq, outmu,
            c * 16384, 16384, base);
    }

    // ---- P5: mixing (full) ----
    mgemm<float, bf16, 0><<<dim3(3 * N / 128, 2), blk, 0, stream>>>(
        outmu, Wvt, nullptr, nullptr, mcat, 3 * N, 128, 256, 128, nullptr);
    mix_pre<<<dim3(N * 128 / 256), blk, 0, stream>>>(mcat, outq, scin, inner, N);
    mgemm<bf16, bf16, 1><<<dim3(N / 128, 3), blk, 0, stream>>>(
        scin, Ws1t, bs1, nullptr, s1, N, 256, 384, 0, nullptr);
    mgemm<bf16, bf16, 0><<<dim3(N / 128, 3), blk, 0, stream>>>(
        s1, Ws2t, bs2, nullptr, delta, N, 384, 384, 0, nullptr);
    mix_post<<<dim3(N * 128 / 256), blk, 0, stream>>>(delta, inner, mcat,
                                                      outq, outmu, N);
}